// Round 6
// baseline (200.422 us; speedup 1.0000x reference)
//
#include <hip/hip_runtime.h>
#include <math.h>

#define VV 128000
#define NB 128
#define PP 2048
#define OO 256

#define S   8         // chunks per row
#define CH  16000     // tokens per chunk
#define CW  500       // CH/32 words
#define NT1 512
#define CAP 512       // LDS survivor slots per chunk
#define HS1 512       // hash slots

#define BIG_NEG_F (-1e30f)
#define PAD_KEY 0x007FFFFF80000000ULL  // packkey(-inf, 0x7fffffff)
#define LOG2E 1.4426950408889634f

__device__ __forceinline__ unsigned long long packkey(float f, int idx) {
  unsigned int b = __float_as_uint(f);
  unsigned int mf = (b & 0x80000000u) ? ~b : (b | 0x80000000u);
  return ((unsigned long long)mf << 32) | (unsigned long long)(unsigned int)(~(unsigned int)idx);
}
__device__ __forceinline__ float unpack_val(unsigned long long k) {
  unsigned int mf = (unsigned int)(k >> 32);
  unsigned int b = (mf & 0x80000000u) ? (mf & 0x7fffffffu) : ~mf;
  return __uint_as_float(b);
}
__device__ __forceinline__ int unpack_idx(unsigned long long k) {
  return (int)(~(unsigned int)(k & 0xffffffffu));
}

// Coherent (agent-scope, per-access sc0|sc1) transport: write-through to the
// coherent point / read bypassing the local (non-cross-XCD-coherent) L2.
// NO fences anywhere -> no buffer_wbl2/buffer_inv whole-L2 flushes (R2 lesson).
__device__ __forceinline__ void st_coh_u64(unsigned long long* p, unsigned long long v) {
  __hip_atomic_store(p, v, __ATOMIC_RELAXED, __HIP_MEMORY_SCOPE_AGENT);
}
__device__ __forceinline__ unsigned long long ld_coh_u64(const unsigned long long* p) {
  return __hip_atomic_load(p, __ATOMIC_RELAXED, __HIP_MEMORY_SCOPE_AGENT);
}
__device__ __forceinline__ void st_coh_f32(float* p, float v) {
  __hip_atomic_store(p, v, __ATOMIC_RELAXED, __HIP_MEMORY_SCOPE_AGENT);
}
__device__ __forceinline__ float ld_coh_f32(const float* p) {
  return __hip_atomic_load(p, __ATOMIC_RELAXED, __HIP_MEMORY_SCOPE_AGENT);
}

// in-register descending bitonic sort across a wave (lane L -> (L+1)-th largest)
__device__ __forceinline__ float wave_sort64_desc(float v, int lane) {
  for (int k = 2; k <= 64; k <<= 1) {
    for (int j = k >> 1; j > 0; j >>= 1) {
      float o = __shfl_xor(v, j, 64);
      bool smaller = (lane & j) == 0;
      bool dir = (lane & k) == 0;
      v = (smaller == dir) ? fmaxf(v, o) : fminf(v, o);
    }
  }
  return v;
}
__device__ __forceinline__ unsigned long long wave_sort64_desc_u64(unsigned long long v, int lane) {
  for (int k = 2; k <= 64; k <<= 1) {
    for (int j = k >> 1; j > 0; j >>= 1) {
      unsigned long long o = __shfl_xor(v, j, 64);
      bool smaller = (lane & j) == 0;
      bool dir = (lane & k) == 0;
      unsigned long long mx = (v > o) ? v : o;
      unsigned long long mn = (v > o) ? o : v;
      v = (smaller == dir) ? mx : mn;
    }
  }
  return v;
}
// merge two sorted-desc 64-runs (v = this wave's run, B = other run in LDS),
// keep top-64 sorted desc. Exact on packed keys (ties included).
__device__ __forceinline__ unsigned long long merge_top64(unsigned long long v,
                                                          const unsigned long long* B,
                                                          int lane) {
  unsigned long long b = B[63 - lane];
  v = (v > b) ? v : b;                  // bitonic top-64 of the union
  for (int j = 32; j > 0; j >>= 1) {    // bitonic clean, descending
    unsigned long long o = __shfl_xor(v, j, 64);
    bool hi = (lane & j) == 0;
    unsigned long long mx = (v > o) ? v : o;
    unsigned long long mn = (v > o) ? o : v;
    v = hi ? mx : mn;
  }
  return v;
}

// ---- single kernel: mask-build + penalize + top-64 + wave0-only finalize ---
// grid (S, NB). Cross-block data via coherent (sc0|sc1) accesses only; the
// completion signal is wave0's vmcnt(0)-ordered relaxed atomicAdd. The last
// block's WAVE 0 ALONE runs the row finalize: no barriers in the protocol.
__global__ __launch_bounds__(NT1, 4)
void k_all(const float* __restrict__ logits,
           const int* __restrict__ prompt_ids,
           const int* __restrict__ output_ids,
           const int* __restrict__ stop_ids,
           const int* __restrict__ min_tokens,
           const float* __restrict__ presence_p,
           const float* __restrict__ frequency_p,
           const float* __restrict__ repetition_p,
           const float* __restrict__ temperature,
           const int* __restrict__ top_k,
           const float* __restrict__ top_p,
           const float* __restrict__ noise,
           int* __restrict__ ws_cnt,
           float* __restrict__ ws_sum,
           unsigned long long* __restrict__ ws_top,
           float* __restrict__ out, int K)
{
#pragma clang fp contract(off)
  __shared__ unsigned int pbits[CW];
  __shared__ unsigned int obits[CW];
  __shared__ int hkey[HS1];
  __shared__ int hval[HS1];
  __shared__ unsigned long long cand[CAP];   // doubles as finalize buf[S*64]
  __shared__ unsigned long long mbuf[4 * 64];
  __shared__ float wtau[NT1 / 64];
  __shared__ float wsum[NT1 / 64];
  __shared__ float tau_sh;
  __shared__ int cnt_sh;
  __shared__ float sv[64];
  __shared__ int   si[64];
  __shared__ float se[64];
  __shared__ float gv[64];

  const int chunk = blockIdx.x;
  const int row   = blockIdx.y;
  const int tid   = threadIdx.x;
  const int lane  = tid & 63;
  const int wv    = tid >> 6;
  const int base  = chunk * CH;

  const float fp  = frequency_p[row];
  const float pp  = presence_p[row];
  const float rp  = repetition_p[row];
  const float inv_rp = 1.0f / rp;
  const float tmp = temperature[row];
  const float t   = (tmp < 1e-5f) ? 1.0f : tmp;
  const float c2  = LOG2E / t;
  const bool need = min_tokens[row] > OO;
  const int s0 = stop_ids[row * 4 + 0];
  const int s1 = stop_ids[row * 4 + 1];
  const int s2 = stop_ids[row * 4 + 2];
  const int s3 = stop_ids[row * 4 + 3];
  const bool anystop = need &&
      (((unsigned)(s0 - base) < CH) || ((unsigned)(s1 - base) < CH) ||
       ((unsigned)(s2 - base) < CH) || ((unsigned)(s3 - base) < CH));

  const float* __restrict__ lrow = logits + (size_t)row * VV + base;
  const int l0 = (0 * NT1 + tid) << 3;
  const int l1 = (1 * NT1 + tid) << 3;
  const int l2 = (2 * NT1 + tid) << 3;
  const int l3 = (3 * NT1 + tid) << 3;
  const bool v3 = l3 < CH;

  // ---- issue ALL logits loads now; latency hides under mask build ----
  float4 A0 = *(const float4*)(lrow + l0);
  float4 B0 = *(const float4*)(lrow + l0 + 4);
  float4 A1 = *(const float4*)(lrow + l1);
  float4 B1 = *(const float4*)(lrow + l1 + 4);
  float4 A2 = *(const float4*)(lrow + l2);
  float4 B2 = *(const float4*)(lrow + l2 + 4);
  float4 A3, B3;
  if (v3) { A3 = *(const float4*)(lrow + l3); B3 = *(const float4*)(lrow + l3 + 4); }

  // ---- build chunk-local bitmasks + count hash in LDS ----
  for (int i = tid; i < CW; i += NT1) { pbits[i] = 0u; obits[i] = 0u; }
  for (int i = tid; i < HS1; i += NT1) { hkey[i] = -1; hval[i] = 0; }
  if (tid == 0) cnt_sh = 0;
  __syncthreads();

  const int4* pr4 = (const int4*)(prompt_ids + (size_t)row * PP);
  for (int i = tid; i < PP / 4; i += NT1) {
    int4 tv = pr4[i];
    int l;
    l = tv.x - base; if ((unsigned)l < CH) atomicOr(&pbits[l >> 5], 1u << (l & 31));
    l = tv.y - base; if ((unsigned)l < CH) atomicOr(&pbits[l >> 5], 1u << (l & 31));
    l = tv.z - base; if ((unsigned)l < CH) atomicOr(&pbits[l >> 5], 1u << (l & 31));
    l = tv.w - base; if ((unsigned)l < CH) atomicOr(&pbits[l >> 5], 1u << (l & 31));
  }
  for (int i = tid; i < OO; i += NT1) {
    int tok = output_ids[row * OO + i];
    int l = tok - base;
    if ((unsigned)l < CH) {
      atomicOr(&obits[l >> 5], 1u << (l & 31));
      unsigned int h = ((unsigned int)tok * 2654435761u) >> 23;
      for (;;) {
        int k = hkey[h];
        if (k == tok) { atomicAdd(&hval[h], 1); break; }
        if (k == -1) {
          int prev = atomicCAS(&hkey[h], -1, tok);
          if (prev == -1 || prev == tok) { atomicAdd(&hval[h], 1); break; }
          continue;
        }
        h = (h + 1) & (HS1 - 1);
      }
    }
  }

  // per-thread stop-token bitmask over its 32 element slots (bit g*8+e)
  unsigned int stopmask = 0u;
  if (anystop) {
    const int sids[4] = {s0, s1, s2, s3};
#pragma unroll
    for (int q = 0; q < 4; ++q) {
      int local = sids[q] - base;
      if ((unsigned)local < CH) {
        int grp = (local >> 3) / NT1;
        int tt  = (local >> 3) % NT1;
        if (tt == tid) stopmask |= 1u << (grp * 8 + (local & 7));
      }
    }
  }
  __syncthreads();

  // ---- phase A: compute EXACT penalized value per element, retain in regs.
  // esum keeps the legacy approx (*inv_rp) sequence -> ws_sum bit-identical.
  float px0[8], px1[8], px2[8], px3[8];
  float gm0 = -INFINITY, gm1 = -INFINITY, gm2 = -INFINITY, gm3 = -INFINITY;
  float esum = 0.0f;

  auto processA = [&](int li, float4 xa, float4 xb, float (&px)[8],
                      float& gm, unsigned int sm8) {
    unsigned int w  = (unsigned)li >> 5;
    unsigned int sh = (unsigned)li & 31u;
    unsigned int pm8 = (pbits[w] >> sh) & 255u;
    unsigned int om8 = (obits[w] >> sh) & 255u;
    float xs[8] = {xa.x, xa.y, xa.z, xa.w, xb.x, xb.y, xb.z, xb.w};
    if (sm8) {                       // rare lanes only; execz-skipped otherwise
#pragma unroll
      for (int e = 0; e < 8; ++e)
        if ((sm8 >> e) & 1u) xs[e] = BIG_NEG_F;
    }
#pragma unroll
    for (int e = 0; e < 8; ++e) {
      float xp = xs[e];
      float xe = xp;                 // exact penalized value
      if ((pm8 | om8) & (1u << e)) {
        float xa_ = (xp > 0.0f) ? (xp * inv_rp) : (xp * rp);  // legacy approx
        float xd_ = (xp > 0.0f) ? (xp / rp)     : (xp * rp);  // exact (ref)
        if ((om8 >> e) & 1u) {
          int v = base + li + e;
          float cnt = 0.0f;
          unsigned int h = ((unsigned int)v * 2654435761u) >> 23;
          for (;;) {
            int k = hkey[h];
            if (k == -1) break;
            if (k == v) { cnt = (float)hval[h]; break; }
            h = (h + 1) & (HS1 - 1);
          }
          xa_ = xa_ - fp * cnt - pp;
          xd_ = xd_ - fp * cnt - pp;
        }
        esum += exp2f(xa_ * c2);
        xe = xd_;
      } else {
        esum += exp2f(xp * c2);
      }
      gm = fmaxf(gm, xe);
      px[e] = xe;
    }
  };

  processA(l0, A0, B0, px0, gm0, stopmask & 255u);
  processA(l1, A1, B1, px1, gm1, (stopmask >> 8) & 255u);
  processA(l2, A2, B2, px2, gm2, (stopmask >> 16) & 255u);
  if (v3) processA(l3, A3, B3, px3, gm3, (stopmask >> 24) & 255u);

  float mx = fmaxf(fmaxf(gm0, gm1), fmaxf(gm2, gm3));

  float ss = esum;
#pragma unroll
  for (int off = 32; off > 0; off >>= 1) ss += __shfl_down(ss, off, 64);
  if (lane == 0) wsum[wv] = ss;

  float srt = wave_sort64_desc(mx, lane);
  if (lane == 7) wtau[wv] = srt;   // wave's 8th-largest thread-max (exact vals)
  __syncthreads();

  if (tid == 0) {
    float tau = wtau[0];
#pragma unroll
    for (int w = 1; w < NT1 / 64; ++w) tau = fminf(tau, wtau[w]);
    tau_sh = tau;                  // exact values -> no ulp slack needed
    float sacc = 0.0f;
#pragma unroll
    for (int w = 0; w < NT1 / 64; ++w) sacc += wsum[w];
    st_coh_f32(&ws_sum[row * S + chunk], sacc);
  }
  __syncthreads();
  const float taueff = tau_sh;

  // ---- phase B: push survivors straight from registers (no reloads) ----
  auto processB = [&](int li, const float (&px)[8], float gmv) {
    if (gmv < taueff) return;
#pragma unroll
    for (int e = 0; e < 8; ++e) {
      float xe = px[e];
      if (xe >= taueff) {
        float xd = xe / t;           // exact reference finalist value
        int p = atomicAdd(&cnt_sh, 1);
        if (p < CAP) cand[p] = packkey(xd, base + li + e);
      }
    }
  };

  processB(l0, px0, gm0);
  processB(l1, px1, gm1);
  processB(l2, px2, gm2);
  if (v3) processB(l3, px3, gm3);

  __syncthreads();
  int total = cnt_sh; if (total > CAP) total = CAP;
  for (int i = tid; i < CAP; i += NT1)
    if (i >= total) cand[i] = PAD_KEY;
  __syncthreads();

  // ---- exact sorted top-64: dynamic tournament sized by survivor count ----
  int runs = (total + 63) >> 6; if (runs < 1) runs = 1;   // block-uniform
  if (wv < runs) {
    unsigned long long rv = wave_sort64_desc_u64(cand[(wv << 6) + lane], lane);
    cand[(wv << 6) + lane] = rv;     // in-segment, no cross-segment hazard
  }
  __syncthreads();

  unsigned long long* outp = &ws_top[((size_t)row * S + chunk) * 64 + lane];
  if (runs > 4) {                               // 8 -> 4 -> 2 -> 1
    if (wv < 4) {
      unsigned long long a = cand[((2 * wv) << 6) + lane];
      a = merge_top64(a, &cand[(2 * wv + 1) << 6], lane);
      mbuf[(wv << 6) + lane] = a;
    }
    __syncthreads();
    if (wv < 2) {
      unsigned long long a = mbuf[((2 * wv) << 6) + lane];
      a = merge_top64(a, &mbuf[(2 * wv + 1) << 6], lane);
      cand[(wv << 6) + lane] = a;
    }
    __syncthreads();
    if (wv == 0) {
      unsigned long long a = cand[lane];
      a = merge_top64(a, &cand[64], lane);
      st_coh_u64(outp, a);
    }
  } else if (runs > 2) {                        // 4 -> 2 -> 1
    if (wv < 2) {
      unsigned long long a = cand[((2 * wv) << 6) + lane];
      a = merge_top64(a, &cand[(2 * wv + 1) << 6], lane);
      mbuf[(wv << 6) + lane] = a;
    }
    __syncthreads();
    if (wv == 0) {
      unsigned long long a = mbuf[lane];
      a = merge_top64(a, &mbuf[64], lane);
      st_coh_u64(outp, a);
    }
  } else if (runs == 2) {                       // 2 -> 1
    if (wv == 0) {
      unsigned long long a = cand[lane];
      a = merge_top64(a, &cand[64], lane);
      st_coh_u64(outp, a);
    }
  } else {                                      // single sorted run
    if (wv == 0) st_coh_u64(outp, cand[lane]);
  }

  // ---- completion protocol: wave0-only, barrier-free ----
  if (wv != 0) return;                 // waves 1..7: zero protocol cost
  // wave 0 issued ALL cross-block stores (ws_top lanes + ws_sum lane0);
  // drain its write-throughs to the coherent point, then signal.
  asm volatile("s_waitcnt vmcnt(0)" ::: "memory");
  int lastv = 0;
  if (lane == 0) lastv = atomicAdd(&ws_cnt[row], 1);
  lastv = __shfl(lastv, 0, 64);
  if (lastv != S - 1) return;
  asm volatile("" ::: "memory");       // pin loads below the acquire branch

  // ---- last block's WAVE 0: merge 8 runs + finalize (single-wave, no bar) --
  const int   tk  = top_k[row];
  const float tpv = top_p[row];

#pragma unroll
  for (int c = 0; c < S; ++c)
    cand[(c << 6) + lane] = ld_coh_u64(&ws_top[((size_t)row * S + c) * 64 + lane]);

  unsigned long long a = cand[lane];   // serial fold: exact same top-64 result
#pragma unroll
  for (int c = 1; c < S; ++c)
    a = merge_top64(a, &cand[c << 6], lane);

  {
    float val = unpack_val(a);
    int   idx = unpack_idx(a);
    float m = __shfl(val, 0, 64);
    sv[lane] = val;
    si[lane] = idx;
    bool ok = (unsigned)idx < VV;
    float u = ok ? noise[(size_t)row * VV + idx] : 0.5f;
    float g = -logf(-logf(u));
    se[lane] = expf(val - m);
    gv[lane] = val / t + g;
  }

  if (lane == 0) {
    float Ssum = 0.0f;
    for (int c = 0; c < S; c++) Ssum += ld_coh_f32(&ws_sum[row * S + c]);
    const float m = sv[0];
    const float Z = Ssum * exp2f(-m * LOG2E);   // full-row softmax denominator

    int keff = (tk < 1) ? 64 : (tk < 64 ? tk : 64);

    float cum = 0.0f;
    int nk = 0;
    for (int j = 0; j < 64; j++) {
      if (j >= keff) break;
      if (!(cum < tpv)) break;
      nk++;
      cum += se[j] / Z;
    }

    float Zk = 0.0f;
    for (int j = 0; j < nk; j++) Zk += se[j];
    const float logZk = logf(Zk);

    float bv = -INFINITY; int bi = 0x7fffffff;
    for (int j = 0; j < nk; j++) {
      float val = gv[j];
      if (val > bv || (val == bv && si[j] < bi)) { bv = val; bi = si[j]; }
    }
    const int samp = (tmp < 1e-5f) ? si[0] : bi;
    out[row] = (float)samp;

    unsigned long long bm0 = 0ull, bm1 = 0ull;
    for (int j = 0; j < nk; j++) {
      int ix = si[j];
      if (ix < 64) bm0 |= 1ull << ix;
      else if (ix < 128) bm1 |= 1ull << (ix - 64);
    }
    int fi = 0;
    for (int j = 0; j < K; j++) {
      float lp; int ix;
      if (j < nk) {
        lp = (sv[j] - m) - logZk;
        ix = si[j];
      } else {
        while ((fi < 64) ? ((bm0 >> fi) & 1ull) : ((bm1 >> (fi - 64)) & 1ull)) fi++;
        ix = fi; fi++;
        lp = BIG_NEG_F;
      }
      out[NB + row * K + j]            = lp;
      out[NB + NB * K + row * K + j]   = (float)ix;
    }
  }
}

extern "C" void kernel_launch(void* const* d_in, const int* in_sizes, int n_in,
                              void* d_out, int out_size, void* d_ws, size_t ws_size,
                              hipStream_t stream) {
  const float* logits = (const float*)d_in[0];
  const int*   prompt = (const int*)d_in[1];
  const int*   outids = (const int*)d_in[2];
  const int*   stop   = (const int*)d_in[3];
  const int*   mint   = (const int*)d_in[4];
  const float* pres   = (const float*)d_in[5];
  const float* freq   = (const float*)d_in[6];
  const float* rep    = (const float*)d_in[7];
  const float* temp   = (const float*)d_in[8];
  const int*   topk   = (const int*)d_in[9];
  const float* topp   = (const float*)d_in[10];
  const float* noise  = (const float*)d_in[11];

  int B_ = in_sizes[4];                     // 128
  int K_ = (out_size - B_) / (2 * B_);      // 20

  // workspace layout: [ws_cnt NB ints][ws_sum NB*S f32][ws_top NB*S*64 u64]
  int* ws_cnt = (int*)d_ws;
  float* ws_sum = (float*)(ws_cnt + NB);
  unsigned long long* ws_top = (unsigned long long*)(ws_sum + (size_t)NB * S);

  hipMemsetAsync(ws_cnt, 0, NB * sizeof(int), stream);
  dim3 g1(S, B_);
  k_all<<<g1, NT1, 0, stream>>>(logits, prompt, outids, stop, mint,
                                pres, freq, rep, temp, topk, topp, noise,
                                ws_cnt, ws_sum, ws_top, (float*)d_out, K_);
}

// Round 8
// 191.502 us; speedup vs baseline: 1.0466x; 1.0466x over previous
//
#include <hip/hip_runtime.h>
#include <math.h>

#define VV 128000
#define NB 128
#define PP 2048
#define OO 256

#define S   8         // chunks per row
#define CH  16000     // tokens per chunk
#define CW  500       // CH/32 words
#define NT1 512
#define CAP 512       // LDS survivor slots per chunk
#define HS1 512       // hash slots

#define NT2 256

#define BIG_NEG_F (-1e30f)
#define PAD_KEY 0x007FFFFF80000000ULL  // packkey(-inf, 0x7fffffff)
#define LOG2E 1.4426950408889634f

__device__ __forceinline__ unsigned long long packkey(float f, int idx) {
  unsigned int b = __float_as_uint(f);
  unsigned int mf = (b & 0x80000000u) ? ~b : (b | 0x80000000u);
  return ((unsigned long long)mf << 32) | (unsigned long long)(unsigned int)(~(unsigned int)idx);
}
__device__ __forceinline__ float unpack_val(unsigned long long k) {
  unsigned int mf = (unsigned int)(k >> 32);
  unsigned int b = (mf & 0x80000000u) ? (mf & 0x7fffffffu) : ~mf;
  return __uint_as_float(b);
}
__device__ __forceinline__ int unpack_idx(unsigned long long k) {
  return (int)(~(unsigned int)(k & 0xffffffffu));
}

// in-register descending bitonic sort across a wave (lane L -> (L+1)-th largest)
__device__ __forceinline__ float wave_sort64_desc(float v, int lane) {
  for (int k = 2; k <= 64; k <<= 1) {
    for (int j = k >> 1; j > 0; j >>= 1) {
      float o = __shfl_xor(v, j, 64);
      bool smaller = (lane & j) == 0;
      bool dir = (lane & k) == 0;
      v = (smaller == dir) ? fmaxf(v, o) : fminf(v, o);
    }
  }
  return v;
}
__device__ __forceinline__ unsigned long long wave_sort64_desc_u64(unsigned long long v, int lane) {
  for (int k = 2; k <= 64; k <<= 1) {
    for (int j = k >> 1; j > 0; j >>= 1) {
      unsigned long long o = __shfl_xor(v, j, 64);
      bool smaller = (lane & j) == 0;
      bool dir = (lane & k) == 0;
      unsigned long long mx = (v > o) ? v : o;
      unsigned long long mn = (v > o) ? o : v;
      v = (smaller == dir) ? mx : mn;
    }
  }
  return v;
}
// merge two sorted-desc 64-runs (v = this wave's run, B = other run in LDS),
// keep top-64 sorted desc. Exact on packed keys (ties included).
__device__ __forceinline__ unsigned long long merge_top64(unsigned long long v,
                                                          const unsigned long long* B,
                                                          int lane) {
  unsigned long long b = B[63 - lane];
  v = (v > b) ? v : b;                  // bitonic top-64 of the union
  for (int j = 32; j > 0; j >>= 1) {    // bitonic clean, descending
    unsigned long long o = __shfl_xor(v, j, 64);
    bool hi = (lane & j) == 0;
    unsigned long long mx = (v > o) ? v : o;
    unsigned long long mn = (v > o) ? o : v;
    v = hi ? mx : mn;
  }
  return v;
}

// ---- kernel 1: mask-build + penalize + exp2-sum + exact sorted top-64 ------
// grid (S, NB). Chunk-local masks/hash in LDS; phase A retains exact values
// in registers; phase B pushes survivors with zero reloads.
__global__ __launch_bounds__(NT1, 4)
void k_main(const float* __restrict__ logits,
            const int* __restrict__ prompt_ids,
            const int* __restrict__ output_ids,
            const int* __restrict__ stop_ids,
            const int* __restrict__ min_tokens,
            const float* __restrict__ presence_p,
            const float* __restrict__ frequency_p,
            const float* __restrict__ repetition_p,
            const float* __restrict__ temperature,
            float* __restrict__ ws_sum,
            unsigned long long* __restrict__ ws_top)
{
#pragma clang fp contract(off)
  __shared__ uint2 masks[CW];        // .x = prompt bits, .y = output bits
  __shared__ int hkey[HS1];
  __shared__ int hval[HS1];
  __shared__ unsigned long long cand[CAP];
  __shared__ unsigned long long mbuf[4 * 64];
  __shared__ float wtau[NT1 / 64];
  __shared__ float wsum[NT1 / 64];
  __shared__ float tau_sh;
  __shared__ int cnt_sh;

  const int chunk = blockIdx.x;
  const int row   = blockIdx.y;
  const int tid   = threadIdx.x;
  const int lane  = tid & 63;
  const int wv    = tid >> 6;
  const int base  = chunk * CH;

  const float fp  = frequency_p[row];
  const float pp  = presence_p[row];
  const float rp  = repetition_p[row];
  const float inv_rp = 1.0f / rp;
  const float tmp = temperature[row];
  const float t   = (tmp < 1e-5f) ? 1.0f : tmp;
  const float c2  = LOG2E / t;
  const bool need = min_tokens[row] > OO;
  const int s0 = stop_ids[row * 4 + 0];
  const int s1 = stop_ids[row * 4 + 1];
  const int s2 = stop_ids[row * 4 + 2];
  const int s3 = stop_ids[row * 4 + 3];
  const bool anystop = need &&
      (((unsigned)(s0 - base) < CH) || ((unsigned)(s1 - base) < CH) ||
       ((unsigned)(s2 - base) < CH) || ((unsigned)(s3 - base) < CH));

  const float* __restrict__ lrow = logits + (size_t)row * VV + base;
  const int l0 = (0 * NT1 + tid) << 3;
  const int l1 = (1 * NT1 + tid) << 3;
  const int l2 = (2 * NT1 + tid) << 3;
  const int l3 = (3 * NT1 + tid) << 3;
  const bool v3 = l3 < CH;

  // ---- issue ALL logits loads now; latency hides under mask build ----
  float4 A0 = *(const float4*)(lrow + l0);
  float4 B0 = *(const float4*)(lrow + l0 + 4);
  float4 A1 = *(const float4*)(lrow + l1);
  float4 B1 = *(const float4*)(lrow + l1 + 4);
  float4 A2 = *(const float4*)(lrow + l2);
  float4 B2 = *(const float4*)(lrow + l2 + 4);
  float4 A3, B3;
  if (v3) { A3 = *(const float4*)(lrow + l3); B3 = *(const float4*)(lrow + l3 + 4); }

  // ---- build chunk-local bitmasks + count hash in LDS ----
  for (int i = tid; i < CW; i += NT1) { masks[i].x = 0u; masks[i].y = 0u; }
  for (int i = tid; i < HS1; i += NT1) { hkey[i] = -1; hval[i] = 0; }
  if (tid == 0) cnt_sh = 0;
  __syncthreads();

  const int4* pr4 = (const int4*)(prompt_ids + (size_t)row * PP);
  for (int i = tid; i < PP / 4; i += NT1) {
    int4 tv = pr4[i];
    int l;
    l = tv.x - base; if ((unsigned)l < CH) atomicOr(&masks[l >> 5].x, 1u << (l & 31));
    l = tv.y - base; if ((unsigned)l < CH) atomicOr(&masks[l >> 5].x, 1u << (l & 31));
    l = tv.z - base; if ((unsigned)l < CH) atomicOr(&masks[l >> 5].x, 1u << (l & 31));
    l = tv.w - base; if ((unsigned)l < CH) atomicOr(&masks[l >> 5].x, 1u << (l & 31));
  }
  for (int i = tid; i < OO; i += NT1) {
    int tok = output_ids[row * OO + i];
    int l = tok - base;
    if ((unsigned)l < CH) {
      atomicOr(&masks[l >> 5].y, 1u << (l & 31));
      unsigned int h = ((unsigned int)tok * 2654435761u) >> 23;
      for (;;) {
        int k = hkey[h];
        if (k == tok) { atomicAdd(&hval[h], 1); break; }
        if (k == -1) {
          int prev = atomicCAS(&hkey[h], -1, tok);
          if (prev == -1 || prev == tok) { atomicAdd(&hval[h], 1); break; }
          continue;
        }
        h = (h + 1) & (HS1 - 1);
      }
    }
  }

  // per-thread stop-token bitmask over its 32 element slots (bit g*8+e)
  unsigned int stopmask = 0u;
  if (anystop) {
    const int sids[4] = {s0, s1, s2, s3};
#pragma unroll
    for (int q = 0; q < 4; ++q) {
      int local = sids[q] - base;
      if ((unsigned)local < CH) {
        int grp = (local >> 3) / NT1;
        int tt  = (local >> 3) % NT1;
        if (tt == tid) stopmask |= 1u << (grp * 8 + (local & 7));
      }
    }
  }
  __syncthreads();

  // ---- phase A: compute EXACT penalized value per element, retain in regs.
  // esum keeps the legacy approx (*inv_rp) sequence -> ws_sum bit-identical.
  float px0[8], px1[8], px2[8], px3[8];
  float gm0 = -INFINITY, gm1 = -INFINITY, gm2 = -INFINITY, gm3 = -INFINITY;
  float esum = 0.0f;

  auto processA = [&](int li, float4 xa, float4 xb, float (&px)[8],
                      float& gm, unsigned int sm8) {
    unsigned int w  = (unsigned)li >> 5;
    unsigned int sh = (unsigned)li & 31u;      // in {0,8,16,24}: never spans word
    uint2 mw = masks[w];                       // one ds_read_b64
    unsigned int pm8 = (mw.x >> sh) & 255u;
    unsigned int om8 = (mw.y >> sh) & 255u;
    float xs[8] = {xa.x, xa.y, xa.z, xa.w, xb.x, xb.y, xb.z, xb.w};
    if (sm8) {                       // rare lanes only; execz-skipped otherwise
#pragma unroll
      for (int e = 0; e < 8; ++e)
        if ((sm8 >> e) & 1u) xs[e] = BIG_NEG_F;
    }
#pragma unroll
    for (int e = 0; e < 8; ++e) {
      float xp = xs[e];
      float xe = xp;                 // exact penalized value
      if ((pm8 | om8) & (1u << e)) {
        float xa_ = (xp > 0.0f) ? (xp * inv_rp) : (xp * rp);  // legacy approx
        float xd_ = (xp > 0.0f) ? (xp / rp)     : (xp * rp);  // exact (ref)
        if ((om8 >> e) & 1u) {
          int v = base + li + e;
          float cnt = 0.0f;
          unsigned int h = ((unsigned int)v * 2654435761u) >> 23;
          for (;;) {
            int k = hkey[h];
            if (k == -1) break;
            if (k == v) { cnt = (float)hval[h]; break; }
            h = (h + 1) & (HS1 - 1);
          }
          xa_ = xa_ - fp * cnt - pp;
          xd_ = xd_ - fp * cnt - pp;
        }
        esum += exp2f(xa_ * c2);
        xe = xd_;
      } else {
        esum += exp2f(xp * c2);
      }
      gm = fmaxf(gm, xe);
      px[e] = xe;
    }
  };

  processA(l0, A0, B0, px0, gm0, stopmask & 255u);
  processA(l1, A1, B1, px1, gm1, (stopmask >> 8) & 255u);
  processA(l2, A2, B2, px2, gm2, (stopmask >> 16) & 255u);
  if (v3) processA(l3, A3, B3, px3, gm3, (stopmask >> 24) & 255u);

  float mx = fmaxf(fmaxf(gm0, gm1), fmaxf(gm2, gm3));

  float ss = esum;
#pragma unroll
  for (int off = 32; off > 0; off >>= 1) ss += __shfl_down(ss, off, 64);
  if (lane == 0) wsum[wv] = ss;

  float srt = wave_sort64_desc(mx, lane);
  if (lane == 7) wtau[wv] = srt;   // wave's 8th-largest thread-max (exact vals)
  __syncthreads();

  if (tid == 0) {
    float tau = wtau[0];
#pragma unroll
    for (int w = 1; w < NT1 / 64; ++w) tau = fminf(tau, wtau[w]);
    tau_sh = tau;                  // exact values -> no ulp slack needed
    float sacc = 0.0f;
#pragma unroll
    for (int w = 0; w < NT1 / 64; ++w) sacc += wsum[w];
    ws_sum[row * S + chunk] = sacc;
  }
  __syncthreads();
  const float taueff = tau_sh;

  // ---- phase B: push survivors straight from registers (no reloads) ----
  auto processB = [&](int li, const float (&px)[8], float gmv) {
    if (gmv < taueff) return;
#pragma unroll
    for (int e = 0; e < 8; ++e) {
      float xe = px[e];
      if (xe >= taueff) {
        float xd = xe / t;           // exact reference finalist value
        int p = atomicAdd(&cnt_sh, 1);
        if (p < CAP) cand[p] = packkey(xd, base + li + e);
      }
    }
  };

  processB(l0, px0, gm0);
  processB(l1, px1, gm1);
  processB(l2, px2, gm2);
  if (v3) processB(l3, px3, gm3);

  __syncthreads();
  int total = cnt_sh; if (total > CAP) total = CAP;
  int runs = (total + 63) >> 6; if (runs < 1) runs = 1;   // block-uniform
  // R7 BUG FIX: the merge tree reads a power-of-two number of segments;
  // pad ALL segments the tree will touch (not just `runs`), else garbage
  // LDS keys poison the top-64.
  const int tree = (runs <= 1) ? 1 : (runs == 2) ? 2 : (runs <= 4) ? 4 : 8;
  const int padto = tree << 6;
  for (int i = tid; i < padto; i += NT1)
    if (i >= total) cand[i] = PAD_KEY;
  __syncthreads();

  // ---- exact sorted top-64: dynamic tournament sized by survivor count ----
  // Segments in [runs, tree) are uniform PAD_KEY (already sorted).
  if (wv < runs) {
    unsigned long long rv = wave_sort64_desc_u64(cand[(wv << 6) + lane], lane);
    cand[(wv << 6) + lane] = rv;     // in-segment, no cross-segment hazard
  }
  __syncthreads();

  unsigned long long* outp = &ws_top[((size_t)row * S + chunk) * 64 + lane];
  if (tree == 8) {                              // 8 -> 4 -> 2 -> 1
    if (wv < 4) {
      unsigned long long a = cand[((2 * wv) << 6) + lane];
      a = merge_top64(a, &cand[(2 * wv + 1) << 6], lane);
      mbuf[(wv << 6) + lane] = a;
    }
    __syncthreads();
    if (wv < 2) {
      unsigned long long a = mbuf[((2 * wv) << 6) + lane];
      a = merge_top64(a, &mbuf[(2 * wv + 1) << 6], lane);
      cand[(wv << 6) + lane] = a;
    }
    __syncthreads();
    if (wv == 0) {
      unsigned long long a = cand[lane];
      a = merge_top64(a, &cand[64], lane);
      *outp = a;
    }
  } else if (tree == 4) {                       // 4 -> 2 -> 1
    if (wv < 2) {
      unsigned long long a = cand[((2 * wv) << 6) + lane];
      a = merge_top64(a, &cand[(2 * wv + 1) << 6], lane);
      mbuf[(wv << 6) + lane] = a;
    }
    __syncthreads();
    if (wv == 0) {
      unsigned long long a = mbuf[lane];
      a = merge_top64(a, &mbuf[64], lane);
      *outp = a;
    }
  } else if (tree == 2) {                       // 2 -> 1
    if (wv == 0) {
      unsigned long long a = cand[lane];
      a = merge_top64(a, &cand[64], lane);
      *outp = a;
    }
  } else {                                      // single sorted run
    if (wv == 0) *outp = cand[lane];
  }
}

// ---------------- kernel 2: register-merge 8 runs + finalize ----------------
__global__ __launch_bounds__(NT2)
void k2_finalize(const float* __restrict__ temperature,
                 const int* __restrict__ top_k,
                 const float* __restrict__ top_p,
                 const float* __restrict__ noise,
                 const unsigned long long* __restrict__ ws_top,
                 const float* __restrict__ ws_sum,
                 float* __restrict__ out, int K)
{
#pragma clang fp contract(off)
  __shared__ unsigned long long buf[S * 64];
  __shared__ unsigned long long mbuf[4 * 64];
  __shared__ float ssh[S];
  __shared__ float sv[64];
  __shared__ int   si[64];
  __shared__ float se[64];
  __shared__ float rr[64];

  const int row  = blockIdx.x;
  const int tid  = threadIdx.x;
  const int lane = tid & 63;
  const int wv   = tid >> 6;      // 4 waves

  const float tmp = temperature[row];
  const float t   = (tmp < 1e-5f) ? 1.0f : tmp;
  const int   tk  = top_k[row];
  const float tpv = top_p[row];

  if (tid < S) ssh[tid] = ws_sum[row * S + tid];   // prefetch, hides under tree
  for (int i = tid; i < S * 64; i += NT2)
    buf[i] = ws_top[(size_t)row * S * 64 + i];
  __syncthreads();

  {                                           // 8 -> 4
    unsigned long long a = buf[((2 * wv) << 6) + lane];
    a = merge_top64(a, &buf[(2 * wv + 1) << 6], lane);
    mbuf[(wv << 6) + lane] = a;
  }
  __syncthreads();
  if (wv < 2) {                               // 4 -> 2
    unsigned long long a = mbuf[((2 * wv) << 6) + lane];
    a = merge_top64(a, &mbuf[(2 * wv + 1) << 6], lane);
    buf[(wv << 6) + lane] = a;
  }
  __syncthreads();
  if (wv != 0) return;                        // wave 0 finishes alone

  // ---- 2 -> 1 + per-lane prep (all wave-local from here: no barriers) ----
  unsigned long long a = buf[lane];
  a = merge_top64(a, &buf[64], lane);
  float val = unpack_val(a);
  int   idx = unpack_idx(a);
  float m = __shfl(val, 0, 64);
  sv[lane] = val;
  si[lane] = idx;
  bool ok = (unsigned)idx < VV;
  float u = ok ? noise[(size_t)row * VV + idx] : 0.5f;
  float g = -logf(-logf(u));
  float sej = expf(val - m);
  se[lane] = sej;
  float gvv = val / t + g;

  // full-row softmax denominator: same serial order as reference (c=0..7)
  float Ssum = 0.0f;
#pragma unroll
  for (int c = 0; c < S; ++c) Ssum += ssh[c];        // uniform across lanes
  const float Z = Ssum * exp2f(-m * LOG2E);
  rr[lane] = sej / Z;                                 // exact per-elem division

  // nk: serial-exact scan; run redundantly on ALL lanes (uniform -> no div.)
  int keff = (tk < 1) ? 64 : (tk < 64 ? tk : 64);
  float cum = 0.0f;
  int nk = 0;
  for (int j = 0; j < 64; j++) {
    if (j >= keff) break;
    if (!(cum < tpv)) break;
    nk++;
    cum += rr[j];
  }

  // argmax over gumbel-perturbed values, exact lexicographic (val desc, idx asc)
  float cv = (lane < nk) ? gvv : -INFINITY;
  int   ci = (lane < nk) ? idx : 0x7fffffff;
#pragma unroll
  for (int off = 32; off > 0; off >>= 1) {
    float ov = __shfl_xor(cv, off, 64);
    int   oi = __shfl_xor(ci, off, 64);
    if (ov > cv || (ov == cv && oi < ci)) { cv = ov; ci = oi; }
  }

  if (lane == 0) {
    float Zk = 0.0f;
    for (int j = 0; j < nk; j++) Zk += se[j];
    const float logZk = logf(Zk);

    const int samp = (tmp < 1e-5f) ? si[0] : ci;
    out[row] = (float)samp;

    unsigned long long bm0 = 0ull, bm1 = 0ull;
    for (int j = 0; j < nk; j++) {
      int ix = si[j];
      if (ix < 64) bm0 |= 1ull << ix;
      else if (ix < 128) bm1 |= 1ull << (ix - 64);
    }
    int fi = 0;
    for (int j = 0; j < K; j++) {
      float lp; int ix;
      if (j < nk) {
        lp = (sv[j] - m) - logZk;
        ix = si[j];
      } else {
        while ((fi < 64) ? ((bm0 >> fi) & 1ull) : ((bm1 >> (fi - 64)) & 1ull)) fi++;
        ix = fi; fi++;
        lp = BIG_NEG_F;
      }
      out[NB + row * K + j]            = lp;
      out[NB + NB * K + row * K + j]   = (float)ix;
    }
  }
}

extern "C" void kernel_launch(void* const* d_in, const int* in_sizes, int n_in,
                              void* d_out, int out_size, void* d_ws, size_t ws_size,
                              hipStream_t stream) {
  const float* logits = (const float*)d_in[0];
  const int*   prompt = (const int*)d_in[1];
  const int*   outids = (const int*)d_in[2];
  const int*   stop   = (const int*)d_in[3];
  const int*   mint   = (const int*)d_in[4];
  const float* pres   = (const float*)d_in[5];
  const float* freq   = (const float*)d_in[6];
  const float* rep    = (const float*)d_in[7];
  const float* temp   = (const float*)d_in[8];
  const int*   topk   = (const int*)d_in[9];
  const float* topp   = (const float*)d_in[10];
  const float* noise  = (const float*)d_in[11];

  int B_ = in_sizes[4];                     // 128
  int K_ = (out_size - B_) / (2 * B_);      // 20

  // workspace layout: [ws_sum NB*S f32][ws_top NB*S*64 u64]
  float* ws_sum = (float*)d_ws;
  unsigned long long* ws_top = (unsigned long long*)(ws_sum + (size_t)NB * S);

  dim3 g1(S, B_);
  k_main<<<g1, NT1, 0, stream>>>(logits, prompt, outids, stop, mint,
                                 pres, freq, rep, temp, ws_sum, ws_top);
  k2_finalize<<<B_, NT2, 0, stream>>>(temp, topk, topp, noise,
                                      ws_top, ws_sum, (float*)d_out, K_);
}

// Round 9
// 184.978 us; speedup vs baseline: 1.0835x; 1.0353x over previous
//
#include <hip/hip_runtime.h>
#include <math.h>

#define VV 128000
#define NB 128
#define PP 2048
#define OO 256

#define S   8         // chunks per row
#define CH  16000     // tokens per chunk
#define CW  500       // CH/32 words
#define NT1 512
#define CAP 512       // LDS survivor slots per chunk
#define HS1 512       // hash slots

#define NT2 256

#define BIG_NEG_F (-1e30f)
#define PAD_KEY 0x007FFFFF80000000ULL  // packkey(-inf, 0x7fffffff)
#define LOG2E 1.4426950408889634f

__device__ __forceinline__ unsigned long long packkey(float f, int idx) {
  unsigned int b = __float_as_uint(f);
  unsigned int mf = (b & 0x80000000u) ? ~b : (b | 0x80000000u);
  return ((unsigned long long)mf << 32) | (unsigned long long)(unsigned int)(~(unsigned int)idx);
}
__device__ __forceinline__ float unpack_val(unsigned long long k) {
  unsigned int mf = (unsigned int)(k >> 32);
  unsigned int b = (mf & 0x80000000u) ? (mf & 0x7fffffffu) : ~mf;
  return __uint_as_float(b);
}
__device__ __forceinline__ int unpack_idx(unsigned long long k) {
  return (int)(~(unsigned int)(k & 0xffffffffu));
}

// in-register descending bitonic sort across a wave (lane L -> (L+1)-th largest)
__device__ __forceinline__ float wave_sort64_desc(float v, int lane) {
  for (int k = 2; k <= 64; k <<= 1) {
    for (int j = k >> 1; j > 0; j >>= 1) {
      float o = __shfl_xor(v, j, 64);
      bool smaller = (lane & j) == 0;
      bool dir = (lane & k) == 0;
      v = (smaller == dir) ? fmaxf(v, o) : fminf(v, o);
    }
  }
  return v;
}
__device__ __forceinline__ unsigned long long wave_sort64_desc_u64(unsigned long long v, int lane) {
  for (int k = 2; k <= 64; k <<= 1) {
    for (int j = k >> 1; j > 0; j >>= 1) {
      unsigned long long o = __shfl_xor(v, j, 64);
      bool smaller = (lane & j) == 0;
      bool dir = (lane & k) == 0;
      unsigned long long mx = (v > o) ? v : o;
      unsigned long long mn = (v > o) ? o : v;
      v = (smaller == dir) ? mx : mn;
    }
  }
  return v;
}
// merge two sorted-desc 64-runs (v = this wave's run, B = other run in LDS),
// keep top-64 sorted desc. Exact on packed keys (ties included).
__device__ __forceinline__ unsigned long long merge_top64(unsigned long long v,
                                                          const unsigned long long* B,
                                                          int lane) {
  unsigned long long b = B[63 - lane];
  v = (v > b) ? v : b;                  // bitonic top-64 of the union
  for (int j = 32; j > 0; j >>= 1) {    // bitonic clean, descending
    unsigned long long o = __shfl_xor(v, j, 64);
    bool hi = (lane & j) == 0;
    unsigned long long mx = (v > o) ? v : o;
    unsigned long long mn = (v > o) ? o : v;
    v = hi ? mx : mn;
  }
  return v;
}

// ---- kernel 1: mask-build + penalize + exp2-sum + exact sorted top-64 ------
// grid (S, NB). Memory schedule: token loads first (consumed by staging under
// counted waits), logits loads issued AFTER the staging barrier so phase A
// pipelines fetch||compute with vmcnt(6/4/2/0) instead of a full drain.
__global__ __launch_bounds__(NT1, 4)
void k_main(const float* __restrict__ logits,
            const int* __restrict__ prompt_ids,
            const int* __restrict__ output_ids,
            const int* __restrict__ stop_ids,
            const int* __restrict__ min_tokens,
            const float* __restrict__ presence_p,
            const float* __restrict__ frequency_p,
            const float* __restrict__ repetition_p,
            const float* __restrict__ temperature,
            float* __restrict__ ws_sum,
            unsigned long long* __restrict__ ws_top)
{
#pragma clang fp contract(off)
  __shared__ uint2 masks[CW];        // .x = prompt bits, .y = output bits
  __shared__ int hkey[HS1];
  __shared__ int hval[HS1];
  __shared__ unsigned long long cand[CAP];
  __shared__ unsigned long long mbuf[4 * 64];
  __shared__ float wtau[NT1 / 64];
  __shared__ float wsum[NT1 / 64];
  __shared__ float tau_sh;
  __shared__ int cnt_sh;

  const int chunk = blockIdx.x;
  const int row   = blockIdx.y;
  const int tid   = threadIdx.x;
  const int lane  = tid & 63;
  const int wv    = tid >> 6;
  const int base  = chunk * CH;

  const float fp  = frequency_p[row];
  const float pp  = presence_p[row];
  const float rp  = repetition_p[row];
  const float inv_rp = 1.0f / rp;
  const float tmp = temperature[row];
  const float t   = (tmp < 1e-5f) ? 1.0f : tmp;
  const float c2  = LOG2E / t;
  const bool need = min_tokens[row] > OO;
  const int s0 = stop_ids[row * 4 + 0];
  const int s1 = stop_ids[row * 4 + 1];
  const int s2 = stop_ids[row * 4 + 2];
  const int s3 = stop_ids[row * 4 + 3];
  const bool anystop = need &&
      (((unsigned)(s0 - base) < CH) || ((unsigned)(s1 - base) < CH) ||
       ((unsigned)(s2 - base) < CH) || ((unsigned)(s3 - base) < CH));

  // ---- token loads FIRST (oldest in VMEM queue; mostly L2-hits) ----
  // PP/4 == NT1: exactly one int4 per thread. OO=256: first half, one int.
  const int4 tv = ((const int4*)(prompt_ids + (size_t)row * PP))[tid];
  const bool havetok = tid < OO;
  int tok = 0;
  if (havetok) tok = output_ids[row * OO + tid];

  // ---- LDS zero-init (no global traffic) ----
  for (int i = tid; i < CW; i += NT1) { masks[i].x = 0u; masks[i].y = 0u; }
  for (int i = tid; i < HS1; i += NT1) { hkey[i] = -1; hval[i] = 0; }
  if (tid == 0) cnt_sh = 0;
  __syncthreads();   // drains only the small token loads

  // ---- scatter masks/hash from registers (LDS-only) ----
  {
    int l;
    l = tv.x - base; if ((unsigned)l < CH) atomicOr(&masks[l >> 5].x, 1u << (l & 31));
    l = tv.y - base; if ((unsigned)l < CH) atomicOr(&masks[l >> 5].x, 1u << (l & 31));
    l = tv.z - base; if ((unsigned)l < CH) atomicOr(&masks[l >> 5].x, 1u << (l & 31));
    l = tv.w - base; if ((unsigned)l < CH) atomicOr(&masks[l >> 5].x, 1u << (l & 31));
  }
  if (havetok) {
    int l = tok - base;
    if ((unsigned)l < CH) {
      atomicOr(&masks[l >> 5].y, 1u << (l & 31));
      unsigned int h = ((unsigned int)tok * 2654435761u) >> 23;
      for (;;) {
        int k = hkey[h];
        if (k == tok) { atomicAdd(&hval[h], 1); break; }
        if (k == -1) {
          int prev = atomicCAS(&hkey[h], -1, tok);
          if (prev == -1 || prev == tok) { atomicAdd(&hval[h], 1); break; }
          continue;
        }
        h = (h + 1) & (HS1 - 1);
      }
    }
  }

  // per-thread stop-token bitmask over its 32 element slots (bit g*8+e)
  unsigned int stopmask = 0u;
  if (anystop) {
    const int sids[4] = {s0, s1, s2, s3};
#pragma unroll
    for (int q = 0; q < 4; ++q) {
      int local = sids[q] - base;
      if ((unsigned)local < CH) {
        int grp = (local >> 3) / NT1;
        int tt  = (local >> 3) % NT1;
        if (tt == tid) stopmask |= 1u << (grp * 8 + (local & 7));
      }
    }
  }
  __syncthreads();   // masks complete; nothing outstanding in VMEM

  // ---- NOW issue logits loads; consume oldest-first => pipelined waits ----
  const float* __restrict__ lrow = logits + (size_t)row * VV + base;
  const int l0 = (0 * NT1 + tid) << 3;
  const int l1 = (1 * NT1 + tid) << 3;
  const int l2 = (2 * NT1 + tid) << 3;
  const int l3 = (3 * NT1 + tid) << 3;
  const bool v3 = l3 < CH;

  float4 A0 = *(const float4*)(lrow + l0);
  float4 B0 = *(const float4*)(lrow + l0 + 4);
  float4 A1 = *(const float4*)(lrow + l1);
  float4 B1 = *(const float4*)(lrow + l1 + 4);
  float4 A2 = *(const float4*)(lrow + l2);
  float4 B2 = *(const float4*)(lrow + l2 + 4);
  float4 A3, B3;
  if (v3) { A3 = *(const float4*)(lrow + l3); B3 = *(const float4*)(lrow + l3 + 4); }

  // ---- phase A: compute EXACT penalized value per element, retain in regs.
  // esum keeps the legacy approx (*inv_rp) sequence -> ws_sum bit-identical.
  float px0[8], px1[8], px2[8], px3[8];
  float gm0 = -INFINITY, gm1 = -INFINITY, gm2 = -INFINITY, gm3 = -INFINITY;
  float esum = 0.0f;

  auto processA = [&](int li, float4 xa, float4 xb, float (&px)[8],
                      float& gm, unsigned int sm8) {
    unsigned int w  = (unsigned)li >> 5;
    unsigned int sh = (unsigned)li & 31u;      // in {0,8,16,24}: never spans word
    uint2 mw = masks[w];                       // one ds_read_b64
    unsigned int pm8 = (mw.x >> sh) & 255u;
    unsigned int om8 = (mw.y >> sh) & 255u;
    float xs[8] = {xa.x, xa.y, xa.z, xa.w, xb.x, xb.y, xb.z, xb.w};
    if (sm8) {                       // rare lanes only; execz-skipped otherwise
#pragma unroll
      for (int e = 0; e < 8; ++e)
        if ((sm8 >> e) & 1u) xs[e] = BIG_NEG_F;
    }
#pragma unroll
    for (int e = 0; e < 8; ++e) {
      float xp = xs[e];
      float xe = xp;                 // exact penalized value
      if ((pm8 | om8) & (1u << e)) {
        float xa_ = (xp > 0.0f) ? (xp * inv_rp) : (xp * rp);  // legacy approx
        float xd_ = (xp > 0.0f) ? (xp / rp)     : (xp * rp);  // exact (ref)
        if ((om8 >> e) & 1u) {
          int v = base + li + e;
          float cnt = 0.0f;
          unsigned int h = ((unsigned int)v * 2654435761u) >> 23;
          for (;;) {
            int k = hkey[h];
            if (k == -1) break;
            if (k == v) { cnt = (float)hval[h]; break; }
            h = (h + 1) & (HS1 - 1);
          }
          xa_ = xa_ - fp * cnt - pp;
          xd_ = xd_ - fp * cnt - pp;
        }
        esum += exp2f(xa_ * c2);
        xe = xd_;
      } else {
        esum += exp2f(xp * c2);
      }
      gm = fmaxf(gm, xe);
      px[e] = xe;
    }
  };

  processA(l0, A0, B0, px0, gm0, stopmask & 255u);
  processA(l1, A1, B1, px1, gm1, (stopmask >> 8) & 255u);
  processA(l2, A2, B2, px2, gm2, (stopmask >> 16) & 255u);
  if (v3) processA(l3, A3, B3, px3, gm3, (stopmask >> 24) & 255u);

  float mx = fmaxf(fmaxf(gm0, gm1), fmaxf(gm2, gm3));

  float ss = esum;
#pragma unroll
  for (int off = 32; off > 0; off >>= 1) ss += __shfl_down(ss, off, 64);
  if (lane == 0) wsum[wv] = ss;

  float srt = wave_sort64_desc(mx, lane);
  if (lane == 7) wtau[wv] = srt;   // wave's 8th-largest thread-max (exact vals)
  __syncthreads();

  if (tid == 0) {
    float tau = wtau[0];
#pragma unroll
    for (int w = 1; w < NT1 / 64; ++w) tau = fminf(tau, wtau[w]);
    tau_sh = tau;                  // exact values -> no ulp slack needed
    float sacc = 0.0f;
#pragma unroll
    for (int w = 0; w < NT1 / 64; ++w) sacc += wsum[w];
    ws_sum[row * S + chunk] = sacc;
  }
  __syncthreads();
  const float taueff = tau_sh;

  // ---- phase B: push survivors straight from registers (no reloads) ----
  auto processB = [&](int li, const float (&px)[8], float gmv) {
    if (gmv < taueff) return;
#pragma unroll
    for (int e = 0; e < 8; ++e) {
      float xe = px[e];
      if (xe >= taueff) {
        float xd = xe / t;           // exact reference finalist value
        int p = atomicAdd(&cnt_sh, 1);
        if (p < CAP) cand[p] = packkey(xd, base + li + e);
      }
    }
  };

  processB(l0, px0, gm0);
  processB(l1, px1, gm1);
  processB(l2, px2, gm2);
  if (v3) processB(l3, px3, gm3);

  __syncthreads();
  int total = cnt_sh; if (total > CAP) total = CAP;
  int runs = (total + 63) >> 6; if (runs < 1) runs = 1;   // block-uniform
  // Pad ALL segments the power-of-two merge tree will read (R7 lesson).
  const int tree = (runs <= 1) ? 1 : (runs == 2) ? 2 : (runs <= 4) ? 4 : 8;
  const int padto = tree << 6;
  for (int i = tid; i < padto; i += NT1)
    if (i >= total) cand[i] = PAD_KEY;
  __syncthreads();

  // ---- exact sorted top-64: dynamic tournament sized by survivor count ----
  // Segments in [runs, tree) are uniform PAD_KEY (already sorted).
  if (wv < runs) {
    unsigned long long rv = wave_sort64_desc_u64(cand[(wv << 6) + lane], lane);
    cand[(wv << 6) + lane] = rv;     // in-segment, no cross-segment hazard
  }
  __syncthreads();

  unsigned long long* outp = &ws_top[((size_t)row * S + chunk) * 64 + lane];
  if (tree == 8) {                              // 8 -> 4 -> 2 -> 1
    if (wv < 4) {
      unsigned long long a = cand[((2 * wv) << 6) + lane];
      a = merge_top64(a, &cand[(2 * wv + 1) << 6], lane);
      mbuf[(wv << 6) + lane] = a;
    }
    __syncthreads();
    if (wv < 2) {
      unsigned long long a = mbuf[((2 * wv) << 6) + lane];
      a = merge_top64(a, &mbuf[(2 * wv + 1) << 6], lane);
      cand[(wv << 6) + lane] = a;
    }
    __syncthreads();
    if (wv == 0) {
      unsigned long long a = cand[lane];
      a = merge_top64(a, &cand[64], lane);
      *outp = a;
    }
  } else if (tree == 4) {                       // 4 -> 2 -> 1
    if (wv < 2) {
      unsigned long long a = cand[((2 * wv) << 6) + lane];
      a = merge_top64(a, &cand[(2 * wv + 1) << 6], lane);
      mbuf[(wv << 6) + lane] = a;
    }
    __syncthreads();
    if (wv == 0) {
      unsigned long long a = mbuf[lane];
      a = merge_top64(a, &mbuf[64], lane);
      *outp = a;
    }
  } else if (tree == 2) {                       // 2 -> 1
    if (wv == 0) {
      unsigned long long a = cand[lane];
      a = merge_top64(a, &cand[64], lane);
      *outp = a;
    }
  } else {                                      // single sorted run
    if (wv == 0) *outp = cand[lane];
  }
}

// ---------------- kernel 2: register-merge 8 runs + finalize ----------------
__global__ __launch_bounds__(NT2)
void k2_finalize(const float* __restrict__ temperature,
                 const int* __restrict__ top_k,
                 const float* __restrict__ top_p,
                 const float* __restrict__ noise,
                 const unsigned long long* __restrict__ ws_top,
                 const float* __restrict__ ws_sum,
                 float* __restrict__ out, int K)
{
#pragma clang fp contract(off)
  __shared__ unsigned long long buf[S * 64];
  __shared__ unsigned long long mbuf[4 * 64];
  __shared__ float ssh[S];
  __shared__ float sv[64];
  __shared__ int   si[64];
  __shared__ float se[64];
  __shared__ float rr[64];

  const int row  = blockIdx.x;
  const int tid  = threadIdx.x;
  const int lane = tid & 63;
  const int wv   = tid >> 6;      // 4 waves

  const float tmp = temperature[row];
  const float t   = (tmp < 1e-5f) ? 1.0f : tmp;
  const int   tk  = top_k[row];
  const float tpv = top_p[row];

  if (tid < S) ssh[tid] = ws_sum[row * S + tid];   // prefetch, hides under tree
  for (int i = tid; i < S * 64; i += NT2)
    buf[i] = ws_top[(size_t)row * S * 64 + i];
  __syncthreads();

  {                                           // 8 -> 4
    unsigned long long a = buf[((2 * wv) << 6) + lane];
    a = merge_top64(a, &buf[(2 * wv + 1) << 6], lane);
    mbuf[(wv << 6) + lane] = a;
  }
  __syncthreads();
  if (wv < 2) {                               // 4 -> 2
    unsigned long long a = mbuf[((2 * wv) << 6) + lane];
    a = merge_top64(a, &mbuf[(2 * wv + 1) << 6], lane);
    buf[(wv << 6) + lane] = a;
  }
  __syncthreads();
  if (wv != 0) return;                        // wave 0 finishes alone

  // ---- 2 -> 1 + per-lane prep (all wave-local from here: no barriers) ----
  unsigned long long a = buf[lane];
  a = merge_top64(a, &buf[64], lane);
  float val = unpack_val(a);
  int   idx = unpack_idx(a);
  float m = __shfl(val, 0, 64);
  sv[lane] = val;
  si[lane] = idx;
  bool ok = (unsigned)idx < VV;
  float u = ok ? noise[(size_t)row * VV + idx] : 0.5f;
  float g = -logf(-logf(u));
  float sej = expf(val - m);
  se[lane] = sej;
  float gvv = val / t + g;

  // full-row softmax denominator: same serial order as reference (c=0..7)
  float Ssum = 0.0f;
#pragma unroll
  for (int c = 0; c < S; ++c) Ssum += ssh[c];        // uniform across lanes
  const float Z = Ssum * exp2f(-m * LOG2E);
  rr[lane] = sej / Z;                                 // exact per-elem division

  // nk: serial-exact scan; run redundantly on ALL lanes (uniform -> no div.)
  int keff = (tk < 1) ? 64 : (tk < 64 ? tk : 64);
  float cum = 0.0f;
  int nk = 0;
  for (int j = 0; j < 64; j++) {
    if (j >= keff) break;
    if (!(cum < tpv)) break;
    nk++;
    cum += rr[j];
  }

  // argmax over gumbel-perturbed values, exact lexicographic (val desc, idx asc)
  float cv = (lane < nk) ? gvv : -INFINITY;
  int   ci = (lane < nk) ? idx : 0x7fffffff;
#pragma unroll
  for (int off = 32; off > 0; off >>= 1) {
    float ov = __shfl_xor(cv, off, 64);
    int   oi = __shfl_xor(ci, off, 64);
    if (ov > cv || (ov == cv && oi < ci)) { cv = ov; ci = oi; }
  }

  if (lane == 0) {
    float Zk = 0.0f;
    for (int j = 0; j < nk; j++) Zk += se[j];
    const float logZk = logf(Zk);

    const int samp = (tmp < 1e-5f) ? si[0] : ci;
    out[row] = (float)samp;

    unsigned long long bm0 = 0ull, bm1 = 0ull;
    for (int j = 0; j < nk; j++) {
      int ix = si[j];
      if (ix < 64) bm0 |= 1ull << ix;
      else if (ix < 128) bm1 |= 1ull << (ix - 64);
    }
    int fi = 0;
    for (int j = 0; j < K; j++) {
      float lp; int ix;
      if (j < nk) {
        lp = (sv[j] - m) - logZk;
        ix = si[j];
      } else {
        while ((fi < 64) ? ((bm0 >> fi) & 1ull) : ((bm1 >> (fi - 64)) & 1ull)) fi++;
        ix = fi; fi++;
        lp = BIG_NEG_F;
      }
      out[NB + row * K + j]            = lp;
      out[NB + NB * K + row * K + j]   = (float)ix;
    }
  }
}

extern "C" void kernel_launch(void* const* d_in, const int* in_sizes, int n_in,
                              void* d_out, int out_size, void* d_ws, size_t ws_size,
                              hipStream_t stream) {
  const float* logits = (const float*)d_in[0];
  const int*   prompt = (const int*)d_in[1];
  const int*   outids = (const int*)d_in[2];
  const int*   stop   = (const int*)d_in[3];
  const int*   mint   = (const int*)d_in[4];
  const float* pres   = (const float*)d_in[5];
  const float* freq   = (const float*)d_in[6];
  const float* rep    = (const float*)d_in[7];
  const float* temp   = (const float*)d_in[8];
  const int*   topk   = (const int*)d_in[9];
  const float* topp   = (const float*)d_in[10];
  const float* noise  = (const float*)d_in[11];

  int B_ = in_sizes[4];                     // 128
  int K_ = (out_size - B_) / (2 * B_);      // 20

  // workspace layout: [ws_sum NB*S f32][ws_top NB*S*64 u64]
  float* ws_sum = (float*)d_ws;
  unsigned long long* ws_top = (unsigned long long*)(ws_sum + (size_t)NB * S);

  dim3 g1(S, B_);
  k_main<<<g1, NT1, 0, stream>>>(logits, prompt, outids, stop, mint,
                                 pres, freq, rep, temp, ws_sum, ws_top);
  k2_finalize<<<B_, NT2, 0, stream>>>(temp, topk, topp, noise,
                                      ws_top, ws_sum, (float*)d_out, K_);
}

// Round 10
// 182.406 us; speedup vs baseline: 1.0988x; 1.0141x over previous
//
#include <hip/hip_runtime.h>
#include <math.h>

#define VV 128000
#define NB 128
#define PP 2048
#define OO 256

#define S   16        // chunks per row (two residency rounds of blocks)
#define CH  8000      // tokens per chunk
#define CW  250       // CH/32 words
#define NT1 512
#define CAP 512       // LDS survivor slots per chunk
#define HS1 512       // hash slots

#define NT2 256

#define BIG_NEG_F (-1e30f)
#define PAD_KEY 0x007FFFFF80000000ULL  // packkey(-inf, 0x7fffffff)
#define LOG2E 1.4426950408889634f

__device__ __forceinline__ unsigned long long packkey(float f, int idx) {
  unsigned int b = __float_as_uint(f);
  unsigned int mf = (b & 0x80000000u) ? ~b : (b | 0x80000000u);
  return ((unsigned long long)mf << 32) | (unsigned long long)(unsigned int)(~(unsigned int)idx);
}
__device__ __forceinline__ float unpack_val(unsigned long long k) {
  unsigned int mf = (unsigned int)(k >> 32);
  unsigned int b = (mf & 0x80000000u) ? (mf & 0x7fffffffu) : ~mf;
  return __uint_as_float(b);
}
__device__ __forceinline__ int unpack_idx(unsigned long long k) {
  return (int)(~(unsigned int)(k & 0xffffffffu));
}

// in-register descending bitonic sort across a wave (lane L -> (L+1)-th largest)
__device__ __forceinline__ float wave_sort64_desc(float v, int lane) {
  for (int k = 2; k <= 64; k <<= 1) {
    for (int j = k >> 1; j > 0; j >>= 1) {
      float o = __shfl_xor(v, j, 64);
      bool smaller = (lane & j) == 0;
      bool dir = (lane & k) == 0;
      v = (smaller == dir) ? fmaxf(v, o) : fminf(v, o);
    }
  }
  return v;
}
__device__ __forceinline__ unsigned long long wave_sort64_desc_u64(unsigned long long v, int lane) {
  for (int k = 2; k <= 64; k <<= 1) {
    for (int j = k >> 1; j > 0; j >>= 1) {
      unsigned long long o = __shfl_xor(v, j, 64);
      bool smaller = (lane & j) == 0;
      bool dir = (lane & k) == 0;
      unsigned long long mx = (v > o) ? v : o;
      unsigned long long mn = (v > o) ? o : v;
      v = (smaller == dir) ? mx : mn;
    }
  }
  return v;
}
// merge two sorted-desc 64-runs (v = this wave's run, B = other run in LDS),
// keep top-64 sorted desc. Exact on packed keys (ties included).
__device__ __forceinline__ unsigned long long merge_top64(unsigned long long v,
                                                          const unsigned long long* B,
                                                          int lane) {
  unsigned long long b = B[63 - lane];
  v = (v > b) ? v : b;                  // bitonic top-64 of the union
  for (int j = 32; j > 0; j >>= 1) {    // bitonic clean, descending
    unsigned long long o = __shfl_xor(v, j, 64);
    bool hi = (lane & j) == 0;
    unsigned long long mx = (v > o) ? v : o;
    unsigned long long mn = (v > o) ? o : v;
    v = hi ? mx : mn;
  }
  return v;
}

// ---- kernel 1: mask-build + penalize + exp2-sum + exact sorted top-64 ------
// grid (S, NB) = 2048 blocks: TWO residency rounds -> round-2 fetch bursts
// overlap round-1 compute/tails (breaks the single-round lockstep stall).
__global__ __launch_bounds__(NT1, 4)
void k_main(const float* __restrict__ logits,
            const int* __restrict__ prompt_ids,
            const int* __restrict__ output_ids,
            const int* __restrict__ stop_ids,
            const int* __restrict__ min_tokens,
            const float* __restrict__ presence_p,
            const float* __restrict__ frequency_p,
            const float* __restrict__ repetition_p,
            const float* __restrict__ temperature,
            float* __restrict__ ws_sum,
            unsigned long long* __restrict__ ws_top)
{
#pragma clang fp contract(off)
  __shared__ uint2 masks[CW];        // .x = prompt bits, .y = output bits
  __shared__ int hkey[HS1];
  __shared__ int hval[HS1];
  __shared__ unsigned long long cand[CAP];
  __shared__ unsigned long long mbuf[4 * 64];
  __shared__ float wtau[NT1 / 64];
  __shared__ float wsum[NT1 / 64];
  __shared__ float tau_sh;
  __shared__ int cnt_sh;

  const int chunk = blockIdx.x;
  const int row   = blockIdx.y;
  const int tid   = threadIdx.x;
  const int lane  = tid & 63;
  const int wv    = tid >> 6;
  const int base  = chunk * CH;

  const float fp  = frequency_p[row];
  const float pp  = presence_p[row];
  const float rp  = repetition_p[row];
  const float inv_rp = 1.0f / rp;
  const float tmp = temperature[row];
  const float t   = (tmp < 1e-5f) ? 1.0f : tmp;
  const float c2  = LOG2E / t;
  const bool need = min_tokens[row] > OO;
  const int s0 = stop_ids[row * 4 + 0];
  const int s1 = stop_ids[row * 4 + 1];
  const int s2 = stop_ids[row * 4 + 2];
  const int s3 = stop_ids[row * 4 + 3];
  const bool anystop = need &&
      (((unsigned)(s0 - base) < CH) || ((unsigned)(s1 - base) < CH) ||
       ((unsigned)(s2 - base) < CH) || ((unsigned)(s3 - base) < CH));

  // ---- token loads FIRST (oldest in VMEM queue; mostly L2-hits) ----
  // PP/4 == NT1: exactly one int4 per thread. OO=256: first half, one int.
  const int4 tv = ((const int4*)(prompt_ids + (size_t)row * PP))[tid];
  const bool havetok = tid < OO;
  int tok = 0;
  if (havetok) tok = output_ids[row * OO + tid];

  // ---- LDS zero-init (no global traffic) ----
  for (int i = tid; i < CW; i += NT1) { masks[i].x = 0u; masks[i].y = 0u; }
  for (int i = tid; i < HS1; i += NT1) { hkey[i] = -1; hval[i] = 0; }
  if (tid == 0) cnt_sh = 0;
  __syncthreads();   // drains only the small token loads

  // ---- scatter masks/hash from registers (LDS-only) ----
  {
    int l;
    l = tv.x - base; if ((unsigned)l < CH) atomicOr(&masks[l >> 5].x, 1u << (l & 31));
    l = tv.y - base; if ((unsigned)l < CH) atomicOr(&masks[l >> 5].x, 1u << (l & 31));
    l = tv.z - base; if ((unsigned)l < CH) atomicOr(&masks[l >> 5].x, 1u << (l & 31));
    l = tv.w - base; if ((unsigned)l < CH) atomicOr(&masks[l >> 5].x, 1u << (l & 31));
  }
  if (havetok) {
    int l = tok - base;
    if ((unsigned)l < CH) {
      atomicOr(&masks[l >> 5].y, 1u << (l & 31));
      unsigned int h = ((unsigned int)tok * 2654435761u) >> 23;
      for (;;) {
        int k = hkey[h];
        if (k == tok) { atomicAdd(&hval[h], 1); break; }
        if (k == -1) {
          int prev = atomicCAS(&hkey[h], -1, tok);
          if (prev == -1 || prev == tok) { atomicAdd(&hval[h], 1); break; }
          continue;
        }
        h = (h + 1) & (HS1 - 1);
      }
    }
  }

  // per-thread stop-token bitmask over its 16 element slots (bit g*8+e)
  unsigned int stopmask = 0u;
  if (anystop) {
    const int sids[4] = {s0, s1, s2, s3};
#pragma unroll
    for (int q = 0; q < 4; ++q) {
      int local = sids[q] - base;
      if ((unsigned)local < CH) {
        int grp = (local >> 3) / NT1;
        int tt  = (local >> 3) % NT1;
        if (tt == tid) stopmask |= 1u << (grp * 8 + (local & 7));
      }
    }
  }
  __syncthreads();   // masks complete; nothing outstanding in VMEM

  // ---- NOW issue logits loads; consume oldest-first => pipelined waits ----
  const float* __restrict__ lrow = logits + (size_t)row * VV + base;
  const int l0 = (0 * NT1 + tid) << 3;
  const int l1 = (1 * NT1 + tid) << 3;
  const bool v1 = l1 < CH;           // 1000 groups: threads 0..487 own a 2nd

  float4 A0 = *(const float4*)(lrow + l0);
  float4 B0 = *(const float4*)(lrow + l0 + 4);
  float4 A1, B1;
  if (v1) { A1 = *(const float4*)(lrow + l1); B1 = *(const float4*)(lrow + l1 + 4); }

  // ---- phase A: compute EXACT penalized value per element, retain in regs.
  float px0[8], px1[8];
  float gm0 = -INFINITY, gm1 = -INFINITY;
  float esum = 0.0f;

  auto processA = [&](int li, float4 xa, float4 xb, float (&px)[8],
                      float& gm, unsigned int sm8) {
    unsigned int w  = (unsigned)li >> 5;
    unsigned int sh = (unsigned)li & 31u;      // in {0,8,16,24}: never spans word
    uint2 mw = masks[w];                       // one ds_read_b64
    unsigned int pm8 = (mw.x >> sh) & 255u;
    unsigned int om8 = (mw.y >> sh) & 255u;
    float xs[8] = {xa.x, xa.y, xa.z, xa.w, xb.x, xb.y, xb.z, xb.w};
    if (sm8) {                       // rare lanes only; execz-skipped otherwise
#pragma unroll
      for (int e = 0; e < 8; ++e)
        if ((sm8 >> e) & 1u) xs[e] = BIG_NEG_F;
    }
#pragma unroll
    for (int e = 0; e < 8; ++e) {
      float xp = xs[e];
      float xe = xp;                 // exact penalized value
      if ((pm8 | om8) & (1u << e)) {
        float xa_ = (xp > 0.0f) ? (xp * inv_rp) : (xp * rp);  // legacy approx
        float xd_ = (xp > 0.0f) ? (xp / rp)     : (xp * rp);  // exact (ref)
        if ((om8 >> e) & 1u) {
          int v = base + li + e;
          float cnt = 0.0f;
          unsigned int h = ((unsigned int)v * 2654435761u) >> 23;
          for (;;) {
            int k = hkey[h];
            if (k == -1) break;
            if (k == v) { cnt = (float)hval[h]; break; }
            h = (h + 1) & (HS1 - 1);
          }
          xa_ = xa_ - fp * cnt - pp;
          xd_ = xd_ - fp * cnt - pp;
        }
        esum += exp2f(xa_ * c2);
        xe = xd_;
      } else {
        esum += exp2f(xp * c2);
      }
      gm = fmaxf(gm, xe);
      px[e] = xe;
    }
  };

  processA(l0, A0, B0, px0, gm0, stopmask & 255u);
  if (v1) processA(l1, A1, B1, px1, gm1, (stopmask >> 8) & 255u);

  float mx = fmaxf(gm0, gm1);

  float ss = esum;
#pragma unroll
  for (int off = 32; off > 0; off >>= 1) ss += __shfl_down(ss, off, 64);
  if (lane == 0) wsum[wv] = ss;

  float srt = wave_sort64_desc(mx, lane);
  if (lane == 7) wtau[wv] = srt;   // 8th-largest thread-max: 8 waves x 8 >= 64
  __syncthreads();

  if (tid == 0) {
    float tau = wtau[0];
#pragma unroll
    for (int w = 1; w < NT1 / 64; ++w) tau = fminf(tau, wtau[w]);
    tau_sh = tau;
    float sacc = 0.0f;
#pragma unroll
    for (int w = 0; w < NT1 / 64; ++w) sacc += wsum[w];
    ws_sum[row * S + chunk] = sacc;
  }
  __syncthreads();
  const float taueff = tau_sh;

  // ---- phase B: push survivors straight from registers (no reloads) ----
  auto processB = [&](int li, const float (&px)[8], float gmv) {
    if (gmv < taueff) return;
#pragma unroll
    for (int e = 0; e < 8; ++e) {
      float xe = px[e];
      if (xe >= taueff) {
        float xd = xe / t;           // exact reference finalist value
        int p = atomicAdd(&cnt_sh, 1);
        if (p < CAP) cand[p] = packkey(xd, base + li + e);
      }
    }
  };

  processB(l0, px0, gm0);
  if (v1) processB(l1, px1, gm1);

  __syncthreads();
  int total = cnt_sh; if (total > CAP) total = CAP;
  int runs = (total + 63) >> 6; if (runs < 1) runs = 1;   // block-uniform
  // Pad ALL segments the power-of-two merge tree will read (R7 lesson).
  const int tree = (runs <= 1) ? 1 : (runs == 2) ? 2 : (runs <= 4) ? 4 : 8;
  const int padto = tree << 6;
  for (int i = tid; i < padto; i += NT1)
    if (i >= total) cand[i] = PAD_KEY;
  __syncthreads();

  // ---- exact sorted top-64: dynamic tournament sized by survivor count ----
  if (wv < runs) {
    unsigned long long rv = wave_sort64_desc_u64(cand[(wv << 6) + lane], lane);
    cand[(wv << 6) + lane] = rv;     // in-segment, no cross-segment hazard
  }
  __syncthreads();

  unsigned long long* outp = &ws_top[((size_t)row * S + chunk) * 64 + lane];
  if (tree == 8) {                              // 8 -> 4 -> 2 -> 1
    if (wv < 4) {
      unsigned long long a = cand[((2 * wv) << 6) + lane];
      a = merge_top64(a, &cand[(2 * wv + 1) << 6], lane);
      mbuf[(wv << 6) + lane] = a;
    }
    __syncthreads();
    if (wv < 2) {
      unsigned long long a = mbuf[((2 * wv) << 6) + lane];
      a = merge_top64(a, &mbuf[(2 * wv + 1) << 6], lane);
      cand[(wv << 6) + lane] = a;
    }
    __syncthreads();
    if (wv == 0) {
      unsigned long long a = cand[lane];
      a = merge_top64(a, &cand[64], lane);
      *outp = a;
    }
  } else if (tree == 4) {                       // 4 -> 2 -> 1
    if (wv < 2) {
      unsigned long long a = cand[((2 * wv) << 6) + lane];
      a = merge_top64(a, &cand[(2 * wv + 1) << 6], lane);
      mbuf[(wv << 6) + lane] = a;
    }
    __syncthreads();
    if (wv == 0) {
      unsigned long long a = mbuf[lane];
      a = merge_top64(a, &mbuf[64], lane);
      *outp = a;
    }
  } else if (tree == 2) {                       // 2 -> 1
    if (wv == 0) {
      unsigned long long a = cand[lane];
      a = merge_top64(a, &cand[64], lane);
      *outp = a;
    }
  } else {                                      // single sorted run
    if (wv == 0) *outp = cand[lane];
  }
}

// ---------------- kernel 2: register-merge 16 runs + finalize ---------------
__global__ __launch_bounds__(NT2)
void k2_finalize(const float* __restrict__ temperature,
                 const int* __restrict__ top_k,
                 const float* __restrict__ top_p,
                 const float* __restrict__ noise,
                 const unsigned long long* __restrict__ ws_top,
                 const float* __restrict__ ws_sum,
                 float* __restrict__ out, int K)
{
#pragma clang fp contract(off)
  __shared__ unsigned long long buf[S * 64];   // 16 runs
  __shared__ unsigned long long mbuf[8 * 64];
  __shared__ float ssh[S];
  __shared__ float sv[64];
  __shared__ int   si[64];
  __shared__ float se[64];
  __shared__ float rr[64];

  const int row  = blockIdx.x;
  const int tid  = threadIdx.x;
  const int lane = tid & 63;
  const int wv   = tid >> 6;      // 4 waves

  const float tmp = temperature[row];
  const float t   = (tmp < 1e-5f) ? 1.0f : tmp;
  const int   tk  = top_k[row];
  const float tpv = top_p[row];

  if (tid < S) ssh[tid] = ws_sum[row * S + tid];   // prefetch, hides under tree
  for (int i = tid; i < S * 64; i += NT2)
    buf[i] = ws_top[(size_t)row * S * 64 + i];
  __syncthreads();

  // 16 -> 8 (each wave merges two pairs)
#pragma unroll
  for (int r = wv; r < 8; r += 4) {
    unsigned long long a = buf[((2 * r) << 6) + lane];
    a = merge_top64(a, &buf[(2 * r + 1) << 6], lane);
    mbuf[(r << 6) + lane] = a;
  }
  __syncthreads();
  {                                           // 8 -> 4
    unsigned long long a = mbuf[((2 * wv) << 6) + lane];
    a = merge_top64(a, &mbuf[(2 * wv + 1) << 6], lane);
    buf[(wv << 6) + lane] = a;
  }
  __syncthreads();
  if (wv < 2) {                               // 4 -> 2
    unsigned long long a = buf[((2 * wv) << 6) + lane];
    a = merge_top64(a, &buf[(2 * wv + 1) << 6], lane);
    mbuf[(wv << 6) + lane] = a;
  }
  __syncthreads();
  if (wv != 0) return;                        // wave 0 finishes alone

  // ---- 2 -> 1 + per-lane prep (all wave-local from here: no barriers) ----
  unsigned long long a = mbuf[lane];
  a = merge_top64(a, &mbuf[64], lane);
  float val = unpack_val(a);
  int   idx = unpack_idx(a);
  float m = __shfl(val, 0, 64);
  sv[lane] = val;
  si[lane] = idx;
  bool ok = (unsigned)idx < VV;
  float u = ok ? noise[(size_t)row * VV + idx] : 0.5f;
  float g = -logf(-logf(u));
  float sej = expf(val - m);
  se[lane] = sej;
  float gvv = val / t + g;

  // full-row softmax denominator (chunk partials, serial c=0..15)
  float Ssum = 0.0f;
#pragma unroll
  for (int c = 0; c < S; ++c) Ssum += ssh[c];        // uniform across lanes
  const float Z = Ssum * exp2f(-m * LOG2E);
  rr[lane] = sej / Z;                                 // exact per-elem division

  // nk: serial-exact scan; run redundantly on ALL lanes (uniform -> no div.)
  int keff = (tk < 1) ? 64 : (tk < 64 ? tk : 64);
  float cum = 0.0f;
  int nk = 0;
  for (int j = 0; j < 64; j++) {
    if (j >= keff) break;
    if (!(cum < tpv)) break;
    nk++;
    cum += rr[j];
  }

  // argmax over gumbel-perturbed values, exact lexicographic (val desc, idx asc)
  float cv = (lane < nk) ? gvv : -INFINITY;
  int   ci = (lane < nk) ? idx : 0x7fffffff;
#pragma unroll
  for (int off = 32; off > 0; off >>= 1) {
    float ov = __shfl_xor(cv, off, 64);
    int   oi = __shfl_xor(ci, off, 64);
    if (ov > cv || (ov == cv && oi < ci)) { cv = ov; ci = oi; }
  }

  if (lane == 0) {
    float Zk = 0.0f;
    for (int j = 0; j < nk; j++) Zk += se[j];
    const float logZk = logf(Zk);

    const int samp = (tmp < 1e-5f) ? si[0] : ci;
    out[row] = (float)samp;

    unsigned long long bm0 = 0ull, bm1 = 0ull;
    for (int j = 0; j < nk; j++) {
      int ix = si[j];
      if (ix < 64) bm0 |= 1ull << ix;
      else if (ix < 128) bm1 |= 1ull << (ix - 64);
    }
    int fi = 0;
    for (int j = 0; j < K; j++) {
      float lp; int ix;
      if (j < nk) {
        lp = (sv[j] - m) - logZk;
        ix = si[j];
      } else {
        while ((fi < 64) ? ((bm0 >> fi) & 1ull) : ((bm1 >> (fi - 64)) & 1ull)) fi++;
        ix = fi; fi++;
        lp = BIG_NEG_F;
      }
      out[NB + row * K + j]            = lp;
      out[NB + NB * K + row * K + j]   = (float)ix;
    }
  }
}

extern "C" void kernel_launch(void* const* d_in, const int* in_sizes, int n_in,
                              void* d_out, int out_size, void* d_ws, size_t ws_size,
                              hipStream_t stream) {
  const float* logits = (const float*)d_in[0];
  const int*   prompt = (const int*)d_in[1];
  const int*   outids = (const int*)d_in[2];
  const int*   stop   = (const int*)d_in[3];
  const int*   mint   = (const int*)d_in[4];
  const float* pres   = (const float*)d_in[5];
  const float* freq   = (const float*)d_in[6];
  const float* rep    = (const float*)d_in[7];
  const float* temp   = (const float*)d_in[8];
  const int*   topk   = (const int*)d_in[9];
  const float* topp   = (const float*)d_in[10];
  const float* noise  = (const float*)d_in[11];

  int B_ = in_sizes[4];                     // 128
  int K_ = (out_size - B_) / (2 * B_);      // 20

  // workspace layout: [ws_sum NB*S f32][ws_top NB*S*64 u64]
  float* ws_sum = (float*)d_ws;
  unsigned long long* ws_top = (unsigned long long*)(ws_sum + (size_t)NB * S);

  dim3 g1(S, B_);
  k_main<<<g1, NT1, 0, stream>>>(logits, prompt, outids, stop, mint,
                                 pres, freq, rep, temp, ws_sum, ws_top);
  k2_finalize<<<B_, NT2, 0, stream>>>(temp, topk, topp, noise,
                                      ws_top, ws_sum, (float*)d_out, K_);
}